// Round 10
// baseline (138.443 us; speedup 1.0000x reference)
//
#include <hip/hip_runtime.h>
#include <hip/hip_bf16.h>

// GRU-D cell: B=16384, I=128, D=16 -- operand-swapped MFMA formulation.
// R9 compute kept verbatim (lane-local gates, zero LDS). R10 changes ONLY the
// work->block geometry: all rounds since R3 plateaued at ~2.2 TB/s effective
// HBM because i-partitioned blocks read scattered 64-B windows of 8-KB rows.
// Fix: i is the FAST grid dim (grid 128x32), so the ~1000 co-resident blocks
// span ALL 128 i's of one contiguous b-slab -> dense line coverage of
// h/gamma/out as the slab marches. i-permutation i=(x%8)*16+x/8 co-locates
// i,i+1 (which share a 128-B line) on the same XCD under round-robin
// linear->XCD mapping, and gives 16-way per-XCD reuse of X/M lines.

typedef float  f32x4_t  __attribute__((ext_vector_type(4)));
typedef short  bf16x8_t __attribute__((ext_vector_type(8)));

constexpr int I_TOT = 128;
constexpr int ROWL  = 2048;   // floats per batch row (I*D)
constexpr int NT    = 8;      // tiles per wave
constexpr int NS    = 128;    // streams per feature (grid.y * 4 waves)

__device__ __forceinline__ unsigned short bf16_rne(float x) {
    union { float f; unsigned u; } c; c.f = x;
    unsigned u = c.u + 0x7fffu + ((c.u >> 16) & 1u);
    return (unsigned short)(u >> 16);
}
__device__ __forceinline__ float bf16_to_f(unsigned short b) {
    union { float f; unsigned u; } c; c.u = ((unsigned)b) << 16;
    return c.f;
}
__device__ __forceinline__ float fast_sigmoid(float x) {
    float e = __expf(-x);
    return __builtin_amdgcn_rcpf(1.0f + e);
}
__device__ __forceinline__ float fast_tanh(float x) {
    x = fminf(fmaxf(x, -10.0f), 10.0f);
    float e = __expf(-2.0f * x);
    return (1.0f - e) * __builtin_amdgcn_rcpf(1.0f + e);
}

struct BPair { bf16x8_t hi, lo; };

// U fragment from 4 f32 values: hi = [h0..h3|h0..h3], lo = [l0..l3|0,0,0,0]
__device__ __forceinline__ BPair build_b(float u0, float u1, float u2, float u3) {
    unsigned short h0 = bf16_rne(u0), h1 = bf16_rne(u1),
                   h2 = bf16_rne(u2), h3 = bf16_rne(u3);
    unsigned short l0 = bf16_rne(u0 - bf16_to_f(h0));
    unsigned short l1 = bf16_rne(u1 - bf16_to_f(h1));
    unsigned short l2 = bf16_rne(u2 - bf16_to_f(h2));
    unsigned short l3 = bf16_rne(u3 - bf16_to_f(h3));
    BPair p;
    p.hi[0] = (short)h0; p.hi[1] = (short)h1; p.hi[2] = (short)h2; p.hi[3] = (short)h3;
    p.hi[4] = (short)h0; p.hi[5] = (short)h1; p.hi[6] = (short)h2; p.hi[7] = (short)h3;
    p.lo[0] = (short)l0; p.lo[1] = (short)l1; p.lo[2] = (short)l2; p.lo[3] = (short)l3;
    p.lo[4] = 0; p.lo[5] = 0; p.lo[6] = 0; p.lo[7] = 0;
    return p;
}

// hh fragment: [hi(a0..a3) | lo(a0..a3)]
__device__ __forceinline__ bf16x8_t build_a(float a0, float a1, float a2, float a3) {
    unsigned short h0 = bf16_rne(a0), h1 = bf16_rne(a1),
                   h2 = bf16_rne(a2), h3 = bf16_rne(a3);
    unsigned short l0 = bf16_rne(a0 - bf16_to_f(h0));
    unsigned short l1 = bf16_rne(a1 - bf16_to_f(h1));
    unsigned short l2 = bf16_rne(a2 - bf16_to_f(h2));
    unsigned short l3 = bf16_rne(a3 - bf16_to_f(h3));
    bf16x8_t A;
    A[0] = (short)h0; A[1] = (short)h1; A[2] = (short)h2; A[3] = (short)h3;
    A[4] = (short)l0; A[5] = (short)l1; A[6] = (short)l2; A[7] = (short)l3;
    return A;
}

__device__ __forceinline__ f32x4_t mm(bf16x8_t a, bf16x8_t b, f32x4_t c) {
    return __builtin_amdgcn_mfma_f32_16x16x32_bf16(a, b, c, 0, 0, 0);
}

__global__ __launch_bounds__(256)
__attribute__((amdgpu_waves_per_eu(2, 8)))
void gru_d_mfma(
    const float* __restrict__ h,
    const float* __restrict__ X,
    const float* __restrict__ M,
    const float* __restrict__ gam,
    const float* __restrict__ W_r, const float* __restrict__ W_z, const float* __restrict__ W_h,
    const float* __restrict__ U_r, const float* __restrict__ U_z, const float* __restrict__ U_h,
    const float* __restrict__ V_r, const float* __restrict__ V_z, const float* __restrict__ V_h,
    const float* __restrict__ b_r, const float* __restrict__ b_z, const float* __restrict__ b_h,
    float* __restrict__ out)
{
    // i from FAST grid dim, permuted so i and i^1 share an XCD:
    // linear block id = x + 128*y; HW xcd ~ linear%8. i=(x%8)*16+x/8 gives
    // each xcd a run of 16 consecutive i's per y-slice.
    const int x  = blockIdx.x;
    const int i  = (x & 7) * 16 + (x >> 3);
    const int t  = threadIdx.x;
    const int w  = t >> 6;              // wave in block
    const int l  = t & 63;              // lane
    const int bi = l & 15;              // batch row within tile
    const int dA = (l >> 4) * 4;        // d-slot / out-col base

    // ---- per-wave parameter fragments (registers, reused over all tiles) ----
    const float* Urp = U_r + i * 256 + bi;   // U[i][d][e=bi]
    const float* Uzp = U_z + i * 256 + bi;
    const float* Uhp = U_h + i * 256 + bi;
    BPair Br = build_b(Urp[(dA+0)*16], Urp[(dA+1)*16], Urp[(dA+2)*16], Urp[(dA+3)*16]);
    BPair Bz = build_b(Uzp[(dA+0)*16], Uzp[(dA+1)*16], Uzp[(dA+2)*16], Uzp[(dA+3)*16]);
    BPair Bh = build_b(Uhp[(dA+0)*16], Uhp[(dA+1)*16], Uhp[(dA+2)*16], Uhp[(dA+3)*16]);
    // Gate-col params at cols dA..dA+3 (per-lane float4, group-uniform)
    const float4 wr4 = *reinterpret_cast<const float4*>(W_r + i*16 + dA);
    const float4 wz4 = *reinterpret_cast<const float4*>(W_z + i*16 + dA);
    const float4 wh4 = *reinterpret_cast<const float4*>(W_h + i*16 + dA);
    const float4 vr4 = *reinterpret_cast<const float4*>(V_r + i*16 + dA);
    const float4 vz4 = *reinterpret_cast<const float4*>(V_z + i*16 + dA);
    const float4 vh4 = *reinterpret_cast<const float4*>(V_h + i*16 + dA);
    const float4 br4 = *reinterpret_cast<const float4*>(b_r + i*16 + dA);
    const float4 bz4 = *reinterpret_cast<const float4*>(b_z + i*16 + dA);
    const float4 bh4 = *reinterpret_cast<const float4*>(b_h + i*16 + dA);

    const int s = blockIdx.y * 4 + w;   // stream id 0..NS-1 (per i)

    // ---- prefetch tile 0 ----
    int b0 = s * 16;
    float4 ph = *reinterpret_cast<const float4*>(h   + (size_t)(b0 + bi) * ROWL + i*16 + dA);
    float4 pg = *reinterpret_cast<const float4*>(gam + (size_t)(b0 + bi) * ROWL + i*16 + dA);
    float px = X[(size_t)(b0 + bi) * I_TOT + i];
    float pm = M[(size_t)(b0 + bi) * I_TOT + i];

    for (int it = 0; it < NT; ++it) {
        // ---- issue next tile's loads (wraps; harmless re-read) ----
        const int b0n = (s + ((it + 1) & (NT - 1)) * NS) * 16;
        float4 nh = *reinterpret_cast<const float4*>(h   + (size_t)(b0n + bi) * ROWL + i*16 + dA);
        float4 ng = *reinterpret_cast<const float4*>(gam + (size_t)(b0n + bi) * ROWL + i*16 + dA);
        float nx = X[(size_t)(b0n + bi) * I_TOT + i];
        float nm = M[(size_t)(b0n + bi) * I_TOT + i];

        // ---- hh = h*gamma: this lane owns hh[b=bi][dA..dA+3] ----
        float hh0 = ph.x * pg.x, hh1 = ph.y * pg.y,
              hh2 = ph.z * pg.z, hh3 = ph.w * pg.w;
        bf16x8_t Ahh = build_a(hh0, hh1, hh2, hh3);

        // ---- r and z gates (transposed): acc[bi][dA+r] in this lane ----
        f32x4_t accR, accZ, accH;
        accR[0] = fmaf(px, wr4.x, fmaf(pm, vr4.x, br4.x));
        accR[1] = fmaf(px, wr4.y, fmaf(pm, vr4.y, br4.y));
        accR[2] = fmaf(px, wr4.z, fmaf(pm, vr4.z, br4.z));
        accR[3] = fmaf(px, wr4.w, fmaf(pm, vr4.w, br4.w));
        accZ[0] = fmaf(px, wz4.x, fmaf(pm, vz4.x, bz4.x));
        accZ[1] = fmaf(px, wz4.y, fmaf(pm, vz4.y, bz4.y));
        accZ[2] = fmaf(px, wz4.z, fmaf(pm, vz4.z, bz4.z));
        accZ[3] = fmaf(px, wz4.w, fmaf(pm, vz4.w, bz4.w));
        accR = mm(Br.hi, Ahh, accR); accR = mm(Br.lo, Ahh, accR);
        accZ = mm(Bz.hi, Ahh, accZ); accZ = mm(Bz.lo, Ahh, accZ);

        // ---- rhh lane-local: rhh[bi][dA+j] = sigmoid(accR[j]) * hh_j ----
        float rh0 = fast_sigmoid(accR[0]) * hh0;
        float rh1 = fast_sigmoid(accR[1]) * hh1;
        float rh2 = fast_sigmoid(accR[2]) * hh2;
        float rh3 = fast_sigmoid(accR[3]) * hh3;
        bf16x8_t Arh = build_a(rh0, rh1, rh2, rh3);

        // ---- h~ gate ----
        accH[0] = fmaf(px, wh4.x, fmaf(pm, vh4.x, bh4.x));
        accH[1] = fmaf(px, wh4.y, fmaf(pm, vh4.y, bh4.y));
        accH[2] = fmaf(px, wh4.z, fmaf(pm, vh4.z, bh4.z));
        accH[3] = fmaf(px, wh4.w, fmaf(pm, vh4.w, bh4.w));
        accH = mm(Bh.hi, Arh, accH); accH = mm(Bh.lo, Arh, accH);

        // ---- out = z*hh + (1-z)*tanh(acch), lane-local, one float4 store ----
        float4 o;
        {
            float z0 = fast_sigmoid(accZ[0]); float t0 = fast_tanh(accH[0]);
            o.x = fmaf(z0, hh0 - t0, t0);
            float z1 = fast_sigmoid(accZ[1]); float t1 = fast_tanh(accH[1]);
            o.y = fmaf(z1, hh1 - t1, t1);
            float z2 = fast_sigmoid(accZ[2]); float t2 = fast_tanh(accH[2]);
            o.z = fmaf(z2, hh2 - t2, t2);
            float z3 = fast_sigmoid(accZ[3]); float t3 = fast_tanh(accH[3]);
            o.w = fmaf(z3, hh3 - t3, t3);
        }
        *reinterpret_cast<float4*>(out + (size_t)(b0 + bi) * ROWL + i*16 + dA) = o;

        // rotate prefetch
        b0 = b0n;
        ph = nh; pg = ng; px = nx; pm = nm;
    }
}

extern "C" void kernel_launch(void* const* d_in, const int* in_sizes, int n_in,
                              void* d_out, int out_size, void* d_ws, size_t ws_size,
                              hipStream_t stream) {
    const float* h       = (const float*)d_in[0];
    const float* X       = (const float*)d_in[1];
    const float* M       = (const float*)d_in[2];
    const float* gamma_h = (const float*)d_in[3];
    const float* W_r     = (const float*)d_in[4];
    const float* W_z     = (const float*)d_in[5];
    const float* W_h     = (const float*)d_in[6];
    const float* U_r     = (const float*)d_in[7];
    const float* U_z     = (const float*)d_in[8];
    const float* U_h     = (const float*)d_in[9];
    const float* V_r     = (const float*)d_in[10];
    const float* V_z     = (const float*)d_in[11];
    const float* V_h     = (const float*)d_in[12];
    const float* b_r     = (const float*)d_in[13];
    const float* b_z     = (const float*)d_in[14];
    const float* b_h     = (const float*)d_in[15];
    float* out = (float*)d_out;

    dim3 grid(I_TOT, NS / 4);   // (128, 32): i is the FAST dimension
    dim3 block(256);
    gru_d_mfma<<<grid, block, 0, stream>>>(h, X, M, gamma_h,
                                           W_r, W_z, W_h,
                                           U_r, U_z, U_h,
                                           V_r, V_z, V_h,
                                           b_r, b_z, b_h,
                                           out);
}